// Round 2
// baseline (246.965 us; speedup 1.0000x reference)
//
#include <hip/hip_runtime.h>

// Problem constants (GATConv_17635135717523)
// N=50000 nodes, E=800000 edges, IN=256, H=8, O=32, H*O=256
#define N_NODES 50000
#define N_EDGES 800000
#define NPAD    50176   // 196*256
#define SPILL_CAP 8192

typedef __bf16 bf16x8 __attribute__((ext_vector_type(8)));
typedef float  fx4    __attribute__((ext_vector_type(4)));
typedef unsigned short us4 __attribute__((ext_vector_type(4)));
typedef unsigned short us8 __attribute__((ext_vector_type(8)));

__device__ __forceinline__ float b2f(unsigned short u) {
    return __uint_as_float(((unsigned)u) << 16);
}
__device__ __forceinline__ unsigned short f2b(float f) {
    unsigned x = __float_as_uint(f);
    return (unsigned short)((x + 0x7FFFu + ((x >> 16) & 1u)) >> 16);
}

// ------------------------------------------------------- W prep + cursor zero
// blocks 0..255: Wt[n][k] = bf16(W[k][n])  (n-major, k contiguous)
// blocks 256..271: M2t[j][k] hi/lo, j<8 -> el head j, j>=8 -> er head j-8
// blocks 272..467: zero cursor (bucket counters); block 272 also zeroes spill_n
__global__ __launch_bounds__(256) void prep_w(
    const float* __restrict__ W,
    const float* __restrict__ attn_l, const float* __restrict__ attn_r,
    unsigned short* __restrict__ Wt,
    unsigned short* __restrict__ M2t_hi, unsigned short* __restrict__ M2t_lo,
    int* __restrict__ cursor, int* __restrict__ spill_n) {
    int b = blockIdx.x, k = threadIdx.x;
    if (b < 256) {
        Wt[b * 256 + k] = f2b(W[k * 256 + b]);
    } else if (b < 272) {
        int j = b - 256;
        const float* av = (j < 8) ? (attn_l + j * 32) : (attn_r + (j - 8) * 32);
        int c0 = (j & 7) * 32;
        float s = 0.f;
#pragma unroll
        for (int o = 0; o < 32; ++o) s += W[k * 256 + c0 + o] * av[o];
        unsigned short h = f2b(s);
        M2t_hi[j * 256 + k] = h;
        M2t_lo[j * 256 + k] = f2b(s - b2f(h));
    } else {
        cursor[(b - 272) * 256 + k] = 0;
        if (b == 272 && k == 0) *spill_n = 0;
    }
}

// ------------------------------------------------------- bucket edges
// Standalone, 1 edge per thread: 0 LDS, minimal VGPR -> near-full occupancy
// (32 waves/CU) so the ~500-900cy atomic->scattered-store chains are hidden
// by TLP. This was previously fused into gemm_ft's tail where occupancy was
// pinned at 12 waves/CU by the GEMM's LDS -- the atomics dominated there.
__global__ __launch_bounds__(256) void bucket(
    const int* __restrict__ src, const int* __restrict__ dst,
    int* __restrict__ cursor, unsigned short* __restrict__ inedge,
    int* __restrict__ spill_n, int2* __restrict__ spill, int stride) {
    int t = blockIdx.x * 256 + threadIdx.x;
    if (t < N_EDGES) {
        int s = src[t], d = dst[t];
        int idx = atomicAdd(&cursor[d], 1);
        if (idx < stride) {
            inedge[(size_t)d * stride + idx] = (unsigned short)s;
        } else {
            int sp = atomicAdd(spill_n, 1);
            if (sp < SPILL_CAP) spill[sp] = make_int2(s, d);
        }
    }
}

// ------------------------------------------------------- fused GEMM
// ft = bf16(feat @ W); el/er = feat @ M2 (fp32 out, M2 in hi+lo bf16).
// Block: 64 rows x 256 cols, 4 waves (wave w owns cols [w*64,w*64+64)).
// Full 64x256 feat tile staged ONCE -> ONE barrier -> 8 barrier-free K-iters.
// Epilogue: acc bounced via LDS (Alds reused after a barrier; LDS total
// 33792 B -> 4 blocks/CU instead of 3) to emit 16B us8 ft stores.
__global__ __launch_bounds__(256) void gemm_ft(
    const float* __restrict__ feat,
    const unsigned short* __restrict__ Wt,
    const unsigned short* __restrict__ M2t_hi,
    const unsigned short* __restrict__ M2t_lo,
    unsigned short* __restrict__ ft,
    float* __restrict__ el, float* __restrict__ er) {
    __shared__ unsigned short Alds[64 * 264];        // 33792 B (also bounce)
    const int tid  = threadIdx.x;
    const int lane = tid & 63;
    const int wid  = tid >> 6;
    const int quad = lane >> 4, l15 = lane & 15;
    const int mbase = blockIdx.x * 64;
    const int nbase = wid * 64;

    fx4 acc[4][4];
    fx4 acce[4];
#pragma unroll
    for (int i = 0; i < 4; ++i) {
        acce[i] = (fx4)0.0f;
#pragma unroll
        for (int j = 0; j < 4; ++j) acc[i][j] = (fx4)0.0f;
    }

    // ---- stage whole tile: thread (srow, squart) covers chunk pairs
    // c8 = ii*8 + squart*2 (chunks of 8 floats); 4-thread cluster = 256B runs.
    {
        const int srow = tid >> 2, squart = tid & 3;
        int grow = mbase + srow;
        grow = grow < N_NODES ? grow : N_NODES - 1;
        const float* sp = feat + (size_t)grow * 256;
        unsigned short* sd = &Alds[srow * 264];
#pragma unroll
        for (int ii = 0; ii < 4; ++ii) {
            int c8 = ii * 8 + squart * 2;
            float4 f0 = *reinterpret_cast<const float4*>(sp + c8 * 8);
            float4 f1 = *reinterpret_cast<const float4*>(sp + c8 * 8 + 4);
            float4 f2 = *reinterpret_cast<const float4*>(sp + c8 * 8 + 8);
            float4 f3 = *reinterpret_cast<const float4*>(sp + c8 * 8 + 12);
            us8 p0, p1;
            p0[0] = f2b(f0.x); p0[1] = f2b(f0.y); p0[2] = f2b(f0.z); p0[3] = f2b(f0.w);
            p0[4] = f2b(f1.x); p0[5] = f2b(f1.y); p0[6] = f2b(f1.z); p0[7] = f2b(f1.w);
            p1[0] = f2b(f2.x); p1[1] = f2b(f2.y); p1[2] = f2b(f2.z); p1[3] = f2b(f2.w);
            p1[4] = f2b(f3.x); p1[5] = f2b(f3.y); p1[6] = f2b(f3.z); p1[7] = f2b(f3.w);
            *reinterpret_cast<us8*>(sd + c8 * 8) = p0;
            *reinterpret_cast<us8*>(sd + c8 * 8 + 8) = p1;
        }
    }
    __syncthreads();

    // ---- K loop, barrier-free
    for (int k0 = 0; k0 < 256; k0 += 32) {
        const int krow = k0 + quad * 8;
        bf16x8 a[4], b[4];
#pragma unroll
        for (int mt = 0; mt < 4; ++mt)
            a[mt] = *reinterpret_cast<const bf16x8*>(&Alds[(mt * 16 + l15) * 264 + krow]);
#pragma unroll
        for (int nt = 0; nt < 4; ++nt)
            b[nt] = *reinterpret_cast<const bf16x8*>(Wt + (nbase + nt * 16 + l15) * 256 + krow);
#pragma unroll
        for (int mt = 0; mt < 4; ++mt)
#pragma unroll
            for (int nt = 0; nt < 4; ++nt)
                acc[mt][nt] = __builtin_amdgcn_mfma_f32_16x16x32_bf16(
                    a[mt], b[nt], acc[mt][nt], 0, 0, 0);
        if (wid == 0) {
            bf16x8 bh = *reinterpret_cast<const bf16x8*>(M2t_hi + l15 * 256 + krow);
            bf16x8 bl = *reinterpret_cast<const bf16x8*>(M2t_lo + l15 * 256 + krow);
#pragma unroll
            for (int mt = 0; mt < 4; ++mt) {
                acce[mt] = __builtin_amdgcn_mfma_f32_16x16x32_bf16(a[mt], bh, acce[mt], 0, 0, 0);
                acce[mt] = __builtin_amdgcn_mfma_f32_16x16x32_bf16(a[mt], bl, acce[mt], 0, 0, 0);
            }
        }
    }
    __syncthreads();   // all waves done reading Alds -> reuse as bounce

    // ---- packed epilogue: per-wave LDS bounce -> us8 (16B) ft stores
    // C/D layout: col = lane&15, row = (lane>>4)*4 + reg  [verified m89/m91]
    unsigned short* bw = &Alds[wid * 1024];   // 2KB per wave, wave-private
#pragma unroll
    for (int mt = 0; mt < 4; ++mt) {
#pragma unroll
        for (int r = 0; r < 4; ++r) {
            int rl = quad * 4 + r;
#pragma unroll
            for (int nt = 0; nt < 4; ++nt)
                bw[rl * 64 + nt * 16 + l15] = f2b(acc[mt][nt][r]);
        }
        // wave-internal ds ordering; compiler inserts lgkmcnt wait
#pragma unroll
        for (int it = 0; it < 2; ++it) {
            int rl = (lane >> 3) + it * 8;
            int c8 = lane & 7;
            us8 v = *reinterpret_cast<const us8*>(&bw[rl * 64 + c8 * 8]);
            int grow = mbase + mt * 16 + rl;
            if (grow < N_NODES)
                *reinterpret_cast<us8*>(ft + (size_t)grow * 256 + nbase + c8 * 8) = v;
        }
    }
    if (wid == 0) {
#pragma unroll
        for (int mt = 0; mt < 4; ++mt) {
#pragma unroll
            for (int r = 0; r < 4; ++r) {
                int row = mbase + mt * 16 + quad * 4 + r;
                if (row < N_NODES) {
                    float v = acce[mt][r];
                    if (l15 < 8) el[row * 8 + l15] = v;
                    else         er[row * 8 + (l15 - 8)] = v;
                }
            }
        }
    }
}

// ------------------------------------------------------- aggregation
// One wave per dst node, single edge pass, HALF-WAVE per edge:
// 32 lanes cover a 512B ft row at 16B/lane (us8); the two halves process
// edge pairs (j, j+1) concurrently; cross-half combine via shfl_xor(32).
// Softmax denom accumulated inline (no max-subtraction; |logit| ~ O(1)).
// Edges come from fixed-stride u16 buckets; deg = cursor[v]; the (expected
// empty) spill list catches any node whose degree exceeded the stride.
__global__ __launch_bounds__(256) void aggregate(
    const unsigned short* __restrict__ ft,
    const float* __restrict__ el, const float* __restrict__ er,
    const int* __restrict__ cursor,
    const unsigned short* __restrict__ inedge,
    const int* __restrict__ spill_n, const int2* __restrict__ spill,
    const float* __restrict__ bias,
    float* __restrict__ out, int stride) {
    int wid = threadIdx.x >> 6, lane = threadIdx.x & 63;
    int v = blockIdx.x * 4 + wid;          // grid exact: v < N always
    int deg_t = cursor[v];
    int deg = deg_t < stride ? deg_t : stride;   // bucketed edges
    int half = lane >> 5, l = lane & 31;
    int h = l >> 2;                         // head of elems [l*8, l*8+8)
    float erv = er[v * 8 + h];
    const unsigned short* ip = inedge + (size_t)v * stride;
    const us8* ft8 = reinterpret_cast<const us8*>(ft);

    float a[8] = {0.f, 0.f, 0.f, 0.f, 0.f, 0.f, 0.f, 0.f};
    float s = 0.f;
    int j = 0;
    for (; j + 8 <= deg; j += 8) {          // 4 pairs = 8 edges per iter
        int u[4];
#pragma unroll
        for (int t = 0; t < 4; ++t) u[t] = ip[j + 2 * t + half];
        us8 f[4];
#pragma unroll
        for (int t = 0; t < 4; ++t) f[t] = ft8[(size_t)u[t] * 32 + l];
#pragma unroll
        for (int t = 0; t < 4; ++t) {
            float x = el[u[t] * 8 + h] + erv;
            x = x > 0.f ? x : 0.2f * x;
            float w = __expf(x);
            s += w;
#pragma unroll
            for (int i = 0; i < 8; ++i) a[i] += w * b2f(f[t][i]);
        }
    }
    for (; j + 2 <= deg; j += 2) {          // pair tail
        int u = ip[j + half];
        us8 f = ft8[(size_t)u * 32 + l];
        float x = el[u * 8 + h] + erv;
        x = x > 0.f ? x : 0.2f * x;
        float w = __expf(x);
        s += w;
#pragma unroll
        for (int i = 0; i < 8; ++i) a[i] += w * b2f(f[i]);
    }
    if (j < deg && half == 0) {             // odd edge: half 0 only
        int u = ip[j];
        us8 f = ft8[(size_t)u * 32 + l];
        float x = el[u * 8 + h] + erv;
        x = x > 0.f ? x : 0.2f * x;
        float w = __expf(x);
        s += w;
#pragma unroll
        for (int i = 0; i < 8; ++i) a[i] += w * b2f(f[i]);
    }
    // spilled edges (expected never taken; correctness net for deg>stride)
    if (deg_t > stride) {
        int sn = *spill_n;
        if (sn > SPILL_CAP) sn = SPILL_CAP;
        for (int t = 0; t < sn; ++t) {
            int2 e = spill[t];
            if (e.y == v && half == 0) {
                int u = e.x;
                us8 f = ft8[(size_t)u * 32 + l];
                float x = el[u * 8 + h] + erv;
                x = x > 0.f ? x : 0.2f * x;
                float w = __expf(x);
                s += w;
#pragma unroll
                for (int i = 0; i < 8; ++i) a[i] += w * b2f(f[i]);
            }
        }
    }
    // combine halves (both halves end with full sums)
#pragma unroll
    for (int i = 0; i < 8; ++i) a[i] += __shfl_xor(a[i], 32);
    s += __shfl_xor(s, 32);
    float inv = deg_t > 0 ? 1.0f / s : 0.f;

    // write: lane stores 4 floats at float4-index l*2+half of the row
    int fi = l * 2 + half;
    float4 bb = reinterpret_cast<const float4*>(bias)[fi];
    int base = half * 4;
    float4 o;
    o.x = a[base + 0] * inv + bb.x;
    o.y = a[base + 1] * inv + bb.y;
    o.z = a[base + 2] * inv + bb.z;
    o.w = a[base + 3] * inv + bb.w;
    reinterpret_cast<float4*>(out)[(size_t)v * 64 + fi] = o;
}

// ------------------------------------------------------- launch (4 dispatches)
extern "C" void kernel_launch(void* const* d_in, const int* in_sizes, int n_in,
                              void* d_out, int out_size, void* d_ws, size_t ws_size,
                              hipStream_t stream) {
    const float* feat   = (const float*)d_in[0];
    const float* W      = (const float*)d_in[1];
    const float* attn_l = (const float*)d_in[2];
    const float* attn_r = (const float*)d_in[3];
    const float* bias   = (const float*)d_in[4];
    const int* src = (const int*)d_in[5];
    const int* dst = (const int*)d_in[6];
    float* out = (float*)d_out;

    char* ws = (char*)d_ws;
    // workspace layout (16B aligned)
    unsigned short* Wt     = (unsigned short*)(ws + 0);          //    131,072
    unsigned short* M2t_hi = (unsigned short*)(ws + 131072);     //      8,192
    unsigned short* M2t_lo = (unsigned short*)(ws + 139264);     //      8,192
    unsigned short* ft     = (unsigned short*)(ws + 147456);     // 25,600,000
    float* el              = (float*)(ws + 25747456);            //  1,600,000
    float* er              = (float*)(ws + 27347456);            //  1,600,000
    int* cursor            = (int*)(ws + 28947456);              //    200,704
    int* spill_n           = (int*)(ws + 29148160);              //         64
    int2* spill            = (int2*)(ws + 29148224);             //     65,536
    unsigned short* inedge = (unsigned short*)(ws + 29213760);   // stride*2*NPAD

    // bucket stride: as many u16 slots per node as the workspace allows,
    // capped at 64 (Poisson(16) degrees; max deg for this dataset ~38).
    // Spill list keeps any overflow exact regardless.
    size_t avail = ws_size > 29213760ull ? ws_size - 29213760ull : 0;
    int stride = (int)(avail / (2ull * NPAD));
    if (stride > 64) stride = 64;

    prep_w<<<468, 256, 0, stream>>>(W, attn_l, attn_r, Wt, M2t_hi, M2t_lo,
                                    cursor, spill_n);
    bucket<<<3125, 256, 0, stream>>>(src, dst, cursor, inedge,
                                     spill_n, spill, stride);
    gemm_ft<<<782, 256, 0, stream>>>(feat, Wt, M2t_hi, M2t_lo, ft, el, er);
    aggregate<<<12500, 256, 0, stream>>>(ft, el, er, cursor, inedge,
                                         spill_n, spill, bias, out, stride);
}

// Round 3
// 225.881 us; speedup vs baseline: 1.0933x; 1.0933x over previous
//
#include <hip/hip_runtime.h>

// Problem constants (GATConv_17635135717523)
// N=50000 nodes, E=800000 edges, IN=256, H=8, O=32, H*O=256
#define N_NODES 50000
#define N_EDGES 800000
#define NPAD    50176   // 196*256
#define SPILL_CAP 8192
#define GEMM_BLOCKS 782
#define BUCKET_BLOCKS 1563   // 1563*512 = 800256 >= E

typedef __bf16 bf16x8 __attribute__((ext_vector_type(8)));
typedef float  fx4    __attribute__((ext_vector_type(4)));
typedef unsigned short us4 __attribute__((ext_vector_type(4)));
typedef unsigned short us8 __attribute__((ext_vector_type(8)));

__device__ __forceinline__ float b2f(unsigned short u) {
    return __uint_as_float(((unsigned)u) << 16);
}
__device__ __forceinline__ unsigned short f2b(float f) {
    unsigned x = __float_as_uint(f);
    return (unsigned short)((x + 0x7FFFu + ((x >> 16) & 1u)) >> 16);
}

// ------------------------------------------------------- W prep + cursor zero
// blocks 0..255: Wt[n][k] = bf16(W[k][n])  (n-major, k contiguous)
// blocks 256..271: M2t[j][k] hi/lo, j<8 -> el head j, j>=8 -> er head j-8
// blocks 272..467: zero cursor (bucket counters); block 272 also zeroes spill_n
__global__ __launch_bounds__(256) void prep_w(
    const float* __restrict__ W,
    const float* __restrict__ attn_l, const float* __restrict__ attn_r,
    unsigned short* __restrict__ Wt,
    unsigned short* __restrict__ M2t_hi, unsigned short* __restrict__ M2t_lo,
    int* __restrict__ cursor, int* __restrict__ spill_n) {
    int b = blockIdx.x, k = threadIdx.x;
    if (b < 256) {
        Wt[b * 256 + k] = f2b(W[k * 256 + b]);
    } else if (b < 272) {
        int j = b - 256;
        const float* av = (j < 8) ? (attn_l + j * 32) : (attn_r + (j - 8) * 32);
        int c0 = (j & 7) * 32;
        float s = 0.f;
#pragma unroll
        for (int o = 0; o < 32; ++o) s += W[k * 256 + c0 + o] * av[o];
        unsigned short h = f2b(s);
        M2t_hi[j * 256 + k] = h;
        M2t_lo[j * 256 + k] = f2b(s - b2f(h));
    } else {
        cursor[(b - 272) * 256 + k] = 0;
        if (b == 272 && k == 0) *spill_n = 0;
    }
}

// ------------------------------------------------------- fused GEMM + bucket
// Heterogeneous grid, 512 threads/block:
//   blocks [0, GEMM_BLOCKS): ft = bf16(feat @ W), el/er = feat @ M2.
//     64 rows x 256 cols, EIGHT waves (wave w owns 32 cols) -> acc 4x2,
//     ~70 VGPR -> 24-32 waves/CU (was 16) to hide staging/Wt-load latency.
//   blocks [GEMM_BLOCKS, +BUCKET_BLOCKS): edge bucketing, 1 edge/thread.
//     Pure latency-bound atomic scatter; backfills CU slots while gemm
//     blocks wait on memory -> its former standalone dispatch disappears.
__global__ __launch_bounds__(512) void gemm_bucket(
    const float* __restrict__ feat,
    const unsigned short* __restrict__ Wt,
    const unsigned short* __restrict__ M2t_hi,
    const unsigned short* __restrict__ M2t_lo,
    unsigned short* __restrict__ ft,
    float* __restrict__ el, float* __restrict__ er,
    const int* __restrict__ src, const int* __restrict__ dst,
    int* __restrict__ cursor, unsigned short* __restrict__ inedge,
    int* __restrict__ spill_n, int2* __restrict__ spill, int stride) {
    __shared__ unsigned short Alds[64 * 264];        // 33792 B (also bounce)

    if (blockIdx.x >= GEMM_BLOCKS) {
        // ---------------- bucket part ----------------
        int t = (blockIdx.x - GEMM_BLOCKS) * 512 + threadIdx.x;
        if (t < N_EDGES) {
            int s = src[t], d = dst[t];
            int idx = atomicAdd(&cursor[d], 1);
            if (idx < stride) {
                inedge[(size_t)d * stride + idx] = (unsigned short)s;
            } else {
                int sp = atomicAdd(spill_n, 1);
                if (sp < SPILL_CAP) spill[sp] = make_int2(s, d);
            }
        }
        return;
    }

    // ---------------- gemm part ----------------
    const int tid  = threadIdx.x;
    const int lane = tid & 63;
    const int wid  = tid >> 6;                       // 0..7
    const int quad = lane >> 4, l15 = lane & 15;
    const int mbase = blockIdx.x * 64;
    const int nbase = wid * 32;

    fx4 acc[4][2];
    fx4 acce[4];
#pragma unroll
    for (int i = 0; i < 4; ++i) {
        acce[i] = (fx4)0.0f;
#pragma unroll
        for (int j = 0; j < 2; ++j) acc[i][j] = (fx4)0.0f;
    }

    // ---- stage whole 64x256 tile: 8 threads per row, 128B each
    {
        const int srow = tid >> 3, s8 = tid & 7;
        int grow = mbase + srow;
        grow = grow < N_NODES ? grow : N_NODES - 1;
        const float* sp = feat + (size_t)grow * 256;
        unsigned short* sd = &Alds[srow * 264];
#pragma unroll
        for (int ii = 0; ii < 2; ++ii) {
            int c8 = ii * 16 + s8 * 2;               // 8-float group index
            float4 f0 = *reinterpret_cast<const float4*>(sp + c8 * 8);
            float4 f1 = *reinterpret_cast<const float4*>(sp + c8 * 8 + 4);
            float4 f2 = *reinterpret_cast<const float4*>(sp + c8 * 8 + 8);
            float4 f3 = *reinterpret_cast<const float4*>(sp + c8 * 8 + 12);
            us8 p0, p1;
            p0[0] = f2b(f0.x); p0[1] = f2b(f0.y); p0[2] = f2b(f0.z); p0[3] = f2b(f0.w);
            p0[4] = f2b(f1.x); p0[5] = f2b(f1.y); p0[6] = f2b(f1.z); p0[7] = f2b(f1.w);
            p1[0] = f2b(f2.x); p1[1] = f2b(f2.y); p1[2] = f2b(f2.z); p1[3] = f2b(f2.w);
            p1[4] = f2b(f3.x); p1[5] = f2b(f3.y); p1[6] = f2b(f3.z); p1[7] = f2b(f3.w);
            *reinterpret_cast<us8*>(sd + c8 * 8) = p0;
            *reinterpret_cast<us8*>(sd + c8 * 8 + 8) = p1;
        }
    }
    __syncthreads();

    // ---- K loop, barrier-free
    for (int k0 = 0; k0 < 256; k0 += 32) {
        const int krow = k0 + quad * 8;
        bf16x8 a[4], b[2];
#pragma unroll
        for (int mt = 0; mt < 4; ++mt)
            a[mt] = *reinterpret_cast<const bf16x8*>(&Alds[(mt * 16 + l15) * 264 + krow]);
#pragma unroll
        for (int nt = 0; nt < 2; ++nt)
            b[nt] = *reinterpret_cast<const bf16x8*>(Wt + (nbase + nt * 16 + l15) * 256 + krow);
#pragma unroll
        for (int mt = 0; mt < 4; ++mt)
#pragma unroll
            for (int nt = 0; nt < 2; ++nt)
                acc[mt][nt] = __builtin_amdgcn_mfma_f32_16x16x32_bf16(
                    a[mt], b[nt], acc[mt][nt], 0, 0, 0);
        if (wid == 0) {
            bf16x8 bh = *reinterpret_cast<const bf16x8*>(M2t_hi + l15 * 256 + krow);
            bf16x8 bl = *reinterpret_cast<const bf16x8*>(M2t_lo + l15 * 256 + krow);
#pragma unroll
            for (int mt = 0; mt < 4; ++mt) {
                acce[mt] = __builtin_amdgcn_mfma_f32_16x16x32_bf16(a[mt], bh, acce[mt], 0, 0, 0);
                acce[mt] = __builtin_amdgcn_mfma_f32_16x16x32_bf16(a[mt], bl, acce[mt], 0, 0, 0);
            }
        }
    }
    __syncthreads();   // all waves done reading Alds -> reuse as bounce

    // ---- packed epilogue: per-wave LDS bounce -> us8 (16B) ft stores
    // C/D layout: col = lane&15, row = (lane>>4)*4 + reg  [verified m89/m91]
    unsigned short* bw = &Alds[wid * 512];   // 1KB per wave, wave-private
#pragma unroll
    for (int mt = 0; mt < 4; ++mt) {
#pragma unroll
        for (int r = 0; r < 4; ++r) {
            int rl = quad * 4 + r;
#pragma unroll
            for (int nt = 0; nt < 2; ++nt)
                bw[rl * 32 + nt * 16 + l15] = f2b(acc[mt][nt][r]);
        }
        // wave-internal ds ordering; compiler inserts lgkmcnt wait
        {
            int rl = lane >> 2;              // 0..15
            int c8 = lane & 3;               // 0..3 (8-short chunks)
            us8 v = *reinterpret_cast<const us8*>(&bw[rl * 32 + c8 * 8]);
            int grow = mbase + mt * 16 + rl;
            if (grow < N_NODES)
                *reinterpret_cast<us8*>(ft + (size_t)grow * 256 + nbase + c8 * 8) = v;
        }
    }
    if (wid == 0) {
#pragma unroll
        for (int mt = 0; mt < 4; ++mt) {
#pragma unroll
            for (int r = 0; r < 4; ++r) {
                int row = mbase + mt * 16 + quad * 4 + r;
                if (row < N_NODES) {
                    float v = acce[mt][r];
                    if (l15 < 8) el[row * 8 + l15] = v;
                    else         er[row * 8 + (l15 - 8)] = v;
                }
            }
        }
    }
}

// ------------------------------------------------------- aggregation
// One wave per dst node, TWO waves per block (grid 25000): finer retirement
// granularity than 4-wave blocks (degree imbalance) and 16 blocks/CU x 2
// waves = full 32-wave occupancy at VGPR 36.
// HALF-WAVE per edge: 32 lanes cover a 512B ft row at 16B/lane (us8); the
// two halves process edge pairs (j, j+1); cross-half combine via shfl_xor(32).
// Softmax denom accumulated inline (no max-subtraction; |logit| ~ O(1)).
__global__ __launch_bounds__(128) void aggregate(
    const unsigned short* __restrict__ ft,
    const float* __restrict__ el, const float* __restrict__ er,
    const int* __restrict__ cursor,
    const unsigned short* __restrict__ inedge,
    const int* __restrict__ spill_n, const int2* __restrict__ spill,
    const float* __restrict__ bias,
    float* __restrict__ out, int stride) {
    int wid = threadIdx.x >> 6, lane = threadIdx.x & 63;
    int v = blockIdx.x * 2 + wid;          // grid exact: v < N always
    int deg_t = cursor[v];
    int deg = deg_t < stride ? deg_t : stride;   // bucketed edges
    int half = lane >> 5, l = lane & 31;
    int h = l >> 2;                         // head of elems [l*8, l*8+8)
    float erv = er[v * 8 + h];
    const unsigned short* ip = inedge + (size_t)v * stride;
    const us8* ft8 = reinterpret_cast<const us8*>(ft);

    float a[8] = {0.f, 0.f, 0.f, 0.f, 0.f, 0.f, 0.f, 0.f};
    float s = 0.f;
    int j = 0;
    for (; j + 8 <= deg; j += 8) {          // 4 pairs = 8 edges per iter
        int u[4];
#pragma unroll
        for (int t = 0; t < 4; ++t) u[t] = ip[j + 2 * t + half];
        us8 f[4];
#pragma unroll
        for (int t = 0; t < 4; ++t) f[t] = ft8[(size_t)u[t] * 32 + l];
#pragma unroll
        for (int t = 0; t < 4; ++t) {
            float x = el[u[t] * 8 + h] + erv;
            x = x > 0.f ? x : 0.2f * x;
            float w = __expf(x);
            s += w;
#pragma unroll
            for (int i = 0; i < 8; ++i) a[i] += w * b2f(f[t][i]);
        }
    }
    for (; j + 2 <= deg; j += 2) {          // pair tail
        int u = ip[j + half];
        us8 f = ft8[(size_t)u * 32 + l];
        float x = el[u * 8 + h] + erv;
        x = x > 0.f ? x : 0.2f * x;
        float w = __expf(x);
        s += w;
#pragma unroll
        for (int i = 0; i < 8; ++i) a[i] += w * b2f(f[i]);
    }
    if (j < deg && half == 0) {             // odd edge: half 0 only
        int u = ip[j];
        us8 f = ft8[(size_t)u * 32 + l];
        float x = el[u * 8 + h] + erv;
        x = x > 0.f ? x : 0.2f * x;
        float w = __expf(x);
        s += w;
#pragma unroll
        for (int i = 0; i < 8; ++i) a[i] += w * b2f(f[i]);
    }
    // spilled edges (expected never taken; correctness net for deg>stride)
    if (deg_t > stride) {
        int sn = *spill_n;
        if (sn > SPILL_CAP) sn = SPILL_CAP;
        for (int t = 0; t < sn; ++t) {
            int2 e = spill[t];
            if (e.y == v && half == 0) {
                int u = e.x;
                us8 f = ft8[(size_t)u * 32 + l];
                float x = el[u * 8 + h] + erv;
                x = x > 0.f ? x : 0.2f * x;
                float w = __expf(x);
                s += w;
#pragma unroll
                for (int i = 0; i < 8; ++i) a[i] += w * b2f(f[i]);
            }
        }
    }
    // combine halves (both halves end with full sums)
#pragma unroll
    for (int i = 0; i < 8; ++i) a[i] += __shfl_xor(a[i], 32);
    s += __shfl_xor(s, 32);
    float inv = deg_t > 0 ? 1.0f / s : 0.f;

    // write: lane stores 4 floats at float4-index l*2+half of the row
    int fi = l * 2 + half;
    float4 bb = reinterpret_cast<const float4*>(bias)[fi];
    int base = half * 4;
    float4 o;
    o.x = a[base + 0] * inv + bb.x;
    o.y = a[base + 1] * inv + bb.y;
    o.z = a[base + 2] * inv + bb.z;
    o.w = a[base + 3] * inv + bb.w;
    reinterpret_cast<float4*>(out)[(size_t)v * 64 + fi] = o;
}

// ------------------------------------------------------- launch (3 dispatches)
extern "C" void kernel_launch(void* const* d_in, const int* in_sizes, int n_in,
                              void* d_out, int out_size, void* d_ws, size_t ws_size,
                              hipStream_t stream) {
    const float* feat   = (const float*)d_in[0];
    const float* W      = (const float*)d_in[1];
    const float* attn_l = (const float*)d_in[2];
    const float* attn_r = (const float*)d_in[3];
    const float* bias   = (const float*)d_in[4];
    const int* src = (const int*)d_in[5];
    const int* dst = (const int*)d_in[6];
    float* out = (float*)d_out;

    char* ws = (char*)d_ws;
    // workspace layout (16B aligned)
    unsigned short* Wt     = (unsigned short*)(ws + 0);          //    131,072
    unsigned short* M2t_hi = (unsigned short*)(ws + 131072);     //      8,192
    unsigned short* M2t_lo = (unsigned short*)(ws + 139264);     //      8,192
    unsigned short* ft     = (unsigned short*)(ws + 147456);     // 25,600,000
    float* el              = (float*)(ws + 25747456);            //  1,600,000
    float* er              = (float*)(ws + 27347456);            //  1,600,000
    int* cursor            = (int*)(ws + 28947456);              //    200,704
    int* spill_n           = (int*)(ws + 29148160);              //         64
    int2* spill            = (int2*)(ws + 29148224);             //     65,536
    unsigned short* inedge = (unsigned short*)(ws + 29213760);   // stride*2*NPAD

    // bucket stride: as many u16 slots per node as the workspace allows,
    // capped at 64 (Poisson(16) degrees; max deg for this dataset ~38).
    // Spill list keeps any overflow exact regardless.
    size_t avail = ws_size > 29213760ull ? ws_size - 29213760ull : 0;
    int stride = (int)(avail / (2ull * NPAD));
    if (stride > 64) stride = 64;

    prep_w<<<468, 256, 0, stream>>>(W, attn_l, attn_r, Wt, M2t_hi, M2t_lo,
                                    cursor, spill_n);
    gemm_bucket<<<GEMM_BLOCKS + BUCKET_BLOCKS, 512, 0, stream>>>(
        feat, Wt, M2t_hi, M2t_lo, ft, el, er,
        src, dst, cursor, inedge, spill_n, spill, stride);
    aggregate<<<25000, 128, 0, stream>>>(ft, el, er, cursor, inedge,
                                         spill_n, spill, bias, out, stride);
}